// Round 4
// baseline (253.522 us; speedup 1.0000x reference)
//
#include <hip/hip_runtime.h>

// MultiHeadAttention: S=2048, B=2, EMB=512, H=8, D=64 -> 16 independent (b,h)
// groups of [2048 x 64] attention, plus per-head 64x64 QKV projections and a
// 512x512 output FC. All matmuls in bf16 MFMA (16x16x32), fp32 accumulate.
//
// R4: flash was TLP-starved (8 waves/CU supplied). Split-K: grid gains a
// key-split dim (NS from ws_size); blocks write (m,l,O^T) fp32 partials,
// combine kernel merges. fc now consumes a pre-converted bf16 W (wconv).
//
// ws (bytes): [0)        Qb  32768x64 bf16   (4 MiB)  Q pre-scaled by 0.125*log2e
//             [4M)       Kb  32768x64 bf16
//             [8M)       Vt  [16][64][2048] bf16
//             [12M)      At  32768x64 bf16
//             [16M)      Wb  512x512 bf16    (512 KiB)
//             [17301504) Opart [2048 strips][NS][64 d][16 q] fp32
//                        MLpart [2048][NS][2][16] fp32

typedef __attribute__((ext_vector_type(8))) __bf16 bf16x8;
typedef __attribute__((ext_vector_type(4))) float f32x4;
typedef __attribute__((ext_vector_type(4))) unsigned short u16x4;
typedef __attribute__((ext_vector_type(4))) unsigned int u32x4;
typedef unsigned short u16;
typedef unsigned int u32;

static __device__ __forceinline__ u16 f2bf(float x) {
    u32 u = __float_as_uint(x);
    u += 0x7fff + ((u >> 16) & 1);   // RNE; inputs are normal floats (no NaN)
    return (u16)(u >> 16);
}
static __device__ __forceinline__ u32 pack2bf(float lo, float hi) {
    u32 a = __float_as_uint(lo), b = __float_as_uint(hi);
    a += 0x7fff + ((a >> 16) & 1);
    b += 0x7fff + ((b >> 16) & 1);
    return (a >> 16) | (b & 0xffff0000u);
}
static __device__ __forceinline__ bf16x8 pack8(float4 a, float4 b) {
    u32x4 r = { pack2bf(a.x, a.y), pack2bf(a.z, a.w),
                pack2bf(b.x, b.y), pack2bf(b.z, b.w) };
    union { u32x4 u; bf16x8 h; } cvt; cvt.u = r; return cvt.h;
}

// ---------------------------------------------------------------------------
// Kernel 1: QKV projection.  Y = (X @ W^T) * scale, X flat [32768 x 64].
// mode 0 -> Qb (scale = 1/sqrt(64)*log2e), 1 -> Kb, 2 -> Vt (transposed
// within group: Vt[(g*64+d)*2048+s]).
// ---------------------------------------------------------------------------
__global__ __launch_bounds__(256) void proj_kernel(
    const float* __restrict__ q, const float* __restrict__ k, const float* __restrict__ v,
    const float* __restrict__ Wq, const float* __restrict__ Wk, const float* __restrict__ Wv,
    u16* __restrict__ Qb, u16* __restrict__ Kb, u16* __restrict__ Vt)
{
    const int mode = blockIdx.z;
    const float* A = (mode == 0) ? q : (mode == 1) ? k : v;
    const float* W = (mode == 0) ? Wq : (mode == 1) ? Wk : Wv;
    const float osc = (mode == 0) ? 0.18033688011112042f : 1.0f; // 0.125*log2(e)

    __shared__ alignas(16) u16 Ssh[128 * 136];

    const int t = threadIdx.x;
    const int m0 = blockIdx.x * 128;
    const int w = t >> 6, l = t & 63;
    const int r16 = l & 15, q4 = l >> 4;

    bf16x8 af[2][2], wf[4][2];
    #pragma unroll
    for (int mc = 0; mc < 2; ++mc)
        #pragma unroll
        for (int kk = 0; kk < 2; ++kk) {
            const float* p = A + (size_t)(m0 + w * 32 + mc * 16 + r16) * 64 + kk * 32 + q4 * 8;
            af[mc][kk] = pack8(*(const float4*)p, *(const float4*)(p + 4));
        }
    #pragma unroll
    for (int nc = 0; nc < 4; ++nc)
        #pragma unroll
        for (int kk = 0; kk < 2; ++kk) {
            const float* p = W + (size_t)(nc * 16 + r16) * 64 + kk * 32 + q4 * 8;
            wf[nc][kk] = pack8(*(const float4*)p, *(const float4*)(p + 4));
        }

    f32x4 acc[2][4];
    const f32x4 zero = {0.f, 0.f, 0.f, 0.f};
    #pragma unroll
    for (int mc = 0; mc < 2; ++mc)
        #pragma unroll
        for (int nc = 0; nc < 4; ++nc) {
            acc[mc][nc] = zero;
            acc[mc][nc] = __builtin_amdgcn_mfma_f32_16x16x32_bf16(af[mc][0], wf[nc][0], acc[mc][nc], 0, 0, 0);
            acc[mc][nc] = __builtin_amdgcn_mfma_f32_16x16x32_bf16(af[mc][1], wf[nc][1], acc[mc][nc], 0, 0, 0);
        }

    // C/D layout: col(n) = lane&15, row(m) = quad*4 + reg
    if (mode < 2) {
        #pragma unroll
        for (int mc = 0; mc < 2; ++mc)
            #pragma unroll
            for (int nc = 0; nc < 4; ++nc)
                #pragma unroll
                for (int r = 0; r < 4; ++r)
                    Ssh[(w * 32 + mc * 16 + q4 * 4 + r) * 72 + nc * 16 + r16] = f2bf(acc[mc][nc][r] * osc);
        __syncthreads();
        u16* Out = ((mode == 0) ? Qb : Kb) + (size_t)m0 * 64;
        int row = t >> 1, cbase = (t & 1) * 32;
        #pragma unroll
        for (int i = 0; i < 4; ++i)
            *(u32x4*)(Out + row * 64 + cbase + i * 8) = *(const u32x4*)(Ssh + row * 72 + cbase + i * 8);
    } else {
        #pragma unroll
        for (int mc = 0; mc < 2; ++mc)
            #pragma unroll
            for (int nc = 0; nc < 4; ++nc)
                #pragma unroll
                for (int r = 0; r < 4; ++r)
                    Ssh[(nc * 16 + r16) * 136 + w * 32 + mc * 16 + q4 * 4 + r] = f2bf(acc[mc][nc][r]);
        __syncthreads();
        const int g = m0 >> 11, s0 = m0 & 2047;
        int d = t >> 2, sb = (t & 3) * 32;
        u16* Out = Vt + ((size_t)(g * 64 + d)) * 2048 + s0;
        #pragma unroll
        for (int i = 0; i < 4; ++i)
            *(u32x4*)(Out + sb + i * 8) = *(const u32x4*)(Ssh + d * 136 + sb + i * 8);
    }
}

// ---------------------------------------------------------------------------
// Kernel 2: split-K flash attention, S^T orientation.  Block = (qt, g, ks);
// covers 64 q rows x kpb keys (kpb = 2048/nsplit), iters of 32 keys.
// nsplit==1: normalize and write Att directly.  nsplit>1: write fp32
// partials (m, l, O^T) for combine_kernel.
// ---------------------------------------------------------------------------
__global__ __launch_bounds__(256, 4) void flash_kernel(
    const u16* __restrict__ Qb, const u16* __restrict__ Kb,
    const u16* __restrict__ Vt, u16* __restrict__ Att,
    float* __restrict__ Opart, float* __restrict__ MLpart,
    int kpb, int nsplit)
{
    const int g = blockIdx.y;    // 0..15
    const int qt = blockIdx.x;   // 0..31
    const int ks = blockIdx.z;   // 0..nsplit-1
    const int t = threadIdx.x, w = t >> 6, l = t & 63;
    const int r16 = l & 15, q4 = l >> 4;

    __shared__ alignas(16) u16 Psh[4][16 * 40];   // per-wave P: [q=16][key=32 pad 40]

    const u16* Kg = Kb + ((size_t)g) * 2048 * 64;
    const u16* Vg = Vt + ((size_t)g) * 64 * 2048;
    const int key0 = ks * kpb;
    const int iters = kpb >> 5;

    // Q B-frag: B[n=q][k=d], lane n=r16, k=q4*8+j (+32)
    bf16x8 qb[2];
    {
        const u16* qp = Qb + ((size_t)(g * 2048 + qt * 64 + w * 16 + r16)) * 64 + q4 * 8;
        qb[0] = *(const bf16x8*)qp;
        qb[1] = *(const bf16x8*)(qp + 32);
    }

    f32x4 o[4];
    const f32x4 zero = {0.f, 0.f, 0.f, 0.f};
    #pragma unroll
    for (int dc = 0; dc < 4; ++dc) o[dc] = zero;
    float m2 = -INFINITY, ls = 0.f;

    // preload K tile 0: A[m=key][k=d], lane m=r16
    bf16x8 ka[2][2];
    #pragma unroll
    for (int kc = 0; kc < 2; ++kc) {
        const u16* kp = Kg + ((size_t)(key0 + kc * 16 + r16)) * 64 + q4 * 8;
        ka[kc][0] = *(const bf16x8*)kp;
        ka[kc][1] = *(const bf16x8*)(kp + 32);
    }

    u16* pw = Psh[w] + r16 * 40;

    for (int it = 0; it < iters; ++it) {
        // V^T A-frags: A[m=d][k=key], lane m=r16
        bf16x8 va[4];
        #pragma unroll
        for (int dc = 0; dc < 4; ++dc)
            va[dc] = *(const bf16x8*)(Vg + ((size_t)(dc * 16 + r16)) * 2048
                                      + key0 + it * 32 + q4 * 8);

        // S^T = K.Q^T : lane holds q-col r16, keys kc*16 + q4*4 + r
        f32x4 s[2];
        #pragma unroll
        for (int kc = 0; kc < 2; ++kc) {
            s[kc] = zero;
            s[kc] = __builtin_amdgcn_mfma_f32_16x16x32_bf16(ka[kc][0], qb[0], s[kc], 0, 0, 0);
            s[kc] = __builtin_amdgcn_mfma_f32_16x16x32_bf16(ka[kc][1], qb[1], s[kc], 0, 0, 0);
        }

        // prefetch next K tile
        const int itn = (it + 1 == iters) ? 0 : it + 1;
        bf16x8 kn[2][2];
        #pragma unroll
        for (int kc = 0; kc < 2; ++kc) {
            const u16* kp = Kg + ((size_t)(key0 + itn * 32 + kc * 16 + r16)) * 64 + q4 * 8;
            kn[kc][0] = *(const bf16x8*)kp;
            kn[kc][1] = *(const bf16x8*)(kp + 32);
        }

        // online softmax (per-lane scalar state, q = r16)
        float mx = fmaxf(fmaxf(fmaxf(s[0][0], s[0][1]), fmaxf(s[0][2], s[0][3])),
                         fmaxf(fmaxf(s[1][0], s[1][1]), fmaxf(s[1][2], s[1][3])));
        mx = fmaxf(mx, __shfl_xor(mx, 16));
        mx = fmaxf(mx, __shfl_xor(mx, 32));
        float mn = fmaxf(m2, mx);
        float alpha = exp2f(m2 - mn);
        m2 = mn;
        float p[2][4];
        float psum = 0.f;
        #pragma unroll
        for (int kc = 0; kc < 2; ++kc)
            #pragma unroll
            for (int r = 0; r < 4; ++r) {
                p[kc][r] = exp2f(s[kc][r] - mn);
                psum += p[kc][r];
            }
        ls = ls * alpha + psum;
        #pragma unroll
        for (int dc = 0; dc < 4; ++dc)
            #pragma unroll
            for (int r = 0; r < 4; ++r) o[dc][r] *= alpha;

        // P^T (C-layout) -> per-wave LDS -> B-frag
        #pragma unroll
        for (int kc = 0; kc < 2; ++kc) {
            uint2 dd = { pack2bf(p[kc][0], p[kc][1]), pack2bf(p[kc][2], p[kc][3]) };
            *(uint2*)(pw + kc * 16 + q4 * 4) = dd;
        }
        bf16x8 pb = *(const bf16x8*)(pw + q4 * 8);  // B[n=q=r16][k=key]

        // O^T += V^T . P^T
        #pragma unroll
        for (int dc = 0; dc < 4; ++dc)
            o[dc] = __builtin_amdgcn_mfma_f32_16x16x32_bf16(va[dc], pb, o[dc], 0, 0, 0);

        #pragma unroll
        for (int kc = 0; kc < 2; ++kc) {
            ka[kc][0] = kn[kc][0];
            ka[kc][1] = kn[kc][1];
        }
    }

    if (nsplit == 1) {
        float lt = ls;
        lt += __shfl_xor(lt, 16);
        lt += __shfl_xor(lt, 32);
        float inv = 1.0f / lt;
        const int qq = qt * 64 + w * 16 + r16;
        u16* orow = Att + ((size_t)(g * 2048 + qq)) * 64;
        #pragma unroll
        for (int dc = 0; dc < 4; ++dc) {
            u16x4 bb = { f2bf(o[dc][0] * inv), f2bf(o[dc][1] * inv),
                         f2bf(o[dc][2] * inv), f2bf(o[dc][3] * inv) };
            *(u16x4*)(orow + dc * 16 + q4 * 4) = bb;
        }
    } else {
        const int strip = (g * 32 + qt) * 4 + w;
        float* op = Opart + ((size_t)strip * nsplit + ks) * 1024;
        #pragma unroll
        for (int dc = 0; dc < 4; ++dc)
            #pragma unroll
            for (int r = 0; r < 4; ++r)
                op[(dc * 16 + q4 * 4 + r) * 16 + r16] = o[dc][r];
        float lt = ls;
        lt += __shfl_xor(lt, 16);
        lt += __shfl_xor(lt, 32);
        if (q4 == 0) {
            float* ml = MLpart + ((size_t)strip * nsplit + ks) * 32;
            ml[r16] = m2;
            ml[16 + r16] = lt;
        }
    }
}

// ---------------------------------------------------------------------------
// Kernel 2b: combine split-K partials -> Att (bf16).  One block per strip
// (16 q rows x 64 d).  Thread t: q = t&15, d-chunk dd = t>>4 (4 d values).
// ---------------------------------------------------------------------------
__global__ __launch_bounds__(256) void combine_kernel(
    const float* __restrict__ Opart, const float* __restrict__ MLpart,
    u16* __restrict__ Att, int nsplit)
{
    const int strip = blockIdx.x;          // 0..2047
    const int t = threadIdx.x;
    const int q = t & 15, dd = t >> 4;     // d = dd*4 .. +3

    const float* mlb = MLpart + (size_t)strip * nsplit * 32;
    float M = -INFINITY;
    for (int ks = 0; ks < nsplit; ++ks) M = fmaxf(M, mlb[ks * 32 + q]);
    float wgt[8];
    float lsum = 0.f;
    for (int ks = 0; ks < nsplit; ++ks) {
        wgt[ks] = exp2f(mlb[ks * 32 + q] - M);
        lsum += mlb[ks * 32 + 16 + q] * wgt[ks];
    }
    float inv = 1.0f / lsum;

    float acc[4] = {0.f, 0.f, 0.f, 0.f};
    const float* ob = Opart + (size_t)strip * nsplit * 1024;
    for (int ks = 0; ks < nsplit; ++ks) {
        float wk = wgt[ks];
        #pragma unroll
        for (int j = 0; j < 4; ++j)
            acc[j] += ob[ks * 1024 + (dd * 4 + j) * 16 + q] * wk;
    }

    const int g = strip >> 7, rem = strip & 127;
    const int qrow = (rem >> 2) * 64 + (rem & 3) * 16 + q;
    u16x4 bb = { f2bf(acc[0] * inv), f2bf(acc[1] * inv),
                 f2bf(acc[2] * inv), f2bf(acc[3] * inv) };
    *(u16x4*)(Att + ((size_t)(g * 2048 + qrow)) * 64 + dd * 4) = bb;
}

// ---------------------------------------------------------------------------
// Kernel 3a: Wfc fp32 -> bf16 (once, 512 KiB, L2-resident for fc).
// ---------------------------------------------------------------------------
__global__ __launch_bounds__(256) void wconv_kernel(
    const float* __restrict__ Wfc, u16* __restrict__ Wb)
{
    int i = (blockIdx.x * 256 + threadIdx.x) * 4;
    float4 v = *(const float4*)(Wfc + i);
    u16x4 b = { f2bf(v.x), f2bf(v.y), f2bf(v.z), f2bf(v.w) };
    *(u16x4*)(Wb + i) = b;
}

// ---------------------------------------------------------------------------
// Kernel 3b: out = Att @ Wb^T + bfc (Wb bf16 row-major [n][k]).
// Zero LDS/barriers; direct b128 fragment loads.  Grid (64,8).
// ---------------------------------------------------------------------------
__global__ __launch_bounds__(256) void fc_kernel(
    const u16* __restrict__ Att, const u16* __restrict__ Wb,
    const float* __restrict__ bfc, float* __restrict__ out)
{
    const int t = threadIdx.x, w = t >> 6, l = t & 63;
    const int r16 = l & 15, q4 = l >> 4;
    const int m0 = blockIdx.x * 64, n0 = blockIdx.y * 64;

    const u16* arow = Att + (size_t)(m0 + w * 16 + r16) * 512 + q4 * 8;

    f32x4 acc[4];
    const f32x4 zero = {0.f, 0.f, 0.f, 0.f};
    #pragma unroll
    for (int nc = 0; nc < 4; ++nc) acc[nc] = zero;

    #pragma unroll 2
    for (int k0 = 0; k0 < 512; k0 += 64) {
        bf16x8 af[2], wf[4][2];
        #pragma unroll
        for (int kk = 0; kk < 2; ++kk)
            af[kk] = *(const bf16x8*)(arow + k0 + kk * 32);
        #pragma unroll
        for (int nc = 0; nc < 4; ++nc)
            #pragma unroll
            for (int kk = 0; kk < 2; ++kk)
                wf[nc][kk] = *(const bf16x8*)(Wb + (size_t)(n0 + nc * 16 + r16) * 512
                                              + k0 + kk * 32 + q4 * 8);
        #pragma unroll
        for (int nc = 0; nc < 4; ++nc) {
            acc[nc] = __builtin_amdgcn_mfma_f32_16x16x32_bf16(af[0], wf[nc][0], acc[nc], 0, 0, 0);
            acc[nc] = __builtin_amdgcn_mfma_f32_16x16x32_bf16(af[1], wf[nc][1], acc[nc], 0, 0, 0);
        }
    }

    #pragma unroll
    for (int nc = 0; nc < 4; ++nc) {
        float bb = bfc[n0 + nc * 16 + r16];
        #pragma unroll
        for (int r = 0; r < 4; ++r) {
            int row = m0 + w * 16 + q4 * 4 + r;
            out[(size_t)row * 512 + n0 + nc * 16 + r16] = acc[nc][r] + bb;
        }
    }
}

// Fallback fc when ws can't even hold Wb: pack W from fp32 in-register.
__global__ __launch_bounds__(256) void fc_f32w_kernel(
    const u16* __restrict__ Att, const float* __restrict__ Wfc,
    const float* __restrict__ bfc, float* __restrict__ out)
{
    const int t = threadIdx.x, w = t >> 6, l = t & 63;
    const int r16 = l & 15, q4 = l >> 4;
    const int m0 = blockIdx.x * 64, n0 = blockIdx.y * 64;
    const u16* arow = Att + (size_t)(m0 + w * 16 + r16) * 512 + q4 * 8;
    f32x4 acc[4];
    const f32x4 zero = {0.f, 0.f, 0.f, 0.f};
    #pragma unroll
    for (int nc = 0; nc < 4; ++nc) acc[nc] = zero;
    for (int k0 = 0; k0 < 512; k0 += 64) {
        bf16x8 af[2], wf[4][2];
        #pragma unroll
        for (int kk = 0; kk < 2; ++kk)
            af[kk] = *(const bf16x8*)(arow + k0 + kk * 32);
        #pragma unroll
        for (int nc = 0; nc < 4; ++nc)
            #pragma unroll
            for (int kk = 0; kk < 2; ++kk) {
                const float* p = Wfc + (size_t)(n0 + nc * 16 + r16) * 512 + k0 + kk * 32 + q4 * 8;
                wf[nc][kk] = pack8(*(const float4*)p, *(const float4*)(p + 4));
            }
        #pragma unroll
        for (int nc = 0; nc < 4; ++nc) {
            acc[nc] = __builtin_amdgcn_mfma_f32_16x16x32_bf16(af[0], wf[nc][0], acc[nc], 0, 0, 0);
            acc[nc] = __builtin_amdgcn_mfma_f32_16x16x32_bf16(af[1], wf[nc][1], acc[nc], 0, 0, 0);
        }
    }
    #pragma unroll
    for (int nc = 0; nc < 4; ++nc) {
        float bb = bfc[n0 + nc * 16 + r16];
        #pragma unroll
        for (int r = 0; r < 4; ++r) {
            int row = m0 + w * 16 + q4 * 4 + r;
            out[(size_t)row * 512 + n0 + nc * 16 + r16] = acc[nc][r] + bb;
        }
    }
}

extern "C" void kernel_launch(void* const* d_in, const int* in_sizes, int n_in,
                              void* d_out, int out_size, void* d_ws, size_t ws_size,
                              hipStream_t stream) {
    (void)in_sizes; (void)n_in; (void)out_size;
    const float* q   = (const float*)d_in[0];
    const float* k   = (const float*)d_in[1];
    const float* v   = (const float*)d_in[2];
    const float* Wq  = (const float*)d_in[3];
    const float* Wk  = (const float*)d_in[4];
    const float* Wv  = (const float*)d_in[5];
    const float* Wfc = (const float*)d_in[6];
    const float* bfc = (const float*)d_in[7];
    float* out = (float*)d_out;

    u16* Qb = (u16*)d_ws;
    u16* Kb = Qb + 2097152;
    u16* Vt = Kb + 2097152;
    u16* At = Vt + 2097152;
    u16* Wb = At + 2097152;                         // ends at byte 17301504
    char* pbase = (char*)d_ws + 17301504;

    const size_t needWb = 17301504;
    auto need = [](int ns) { return (size_t)17301504 + (size_t)ns * 8650752; };
    int ns = (ws_size >= need(4)) ? 4 : (ws_size >= need(2)) ? 2 : 1;
    bool haveWb = ws_size >= needWb;

    proj_kernel<<<dim3(256, 1, 3), 256, 0, stream>>>(q, k, v, Wq, Wk, Wv, Qb, Kb, Vt);

    if (ns > 1) {
        float* Opart  = (float*)pbase;
        float* MLpart = (float*)(pbase + (size_t)ns * 8388608);
        flash_kernel<<<dim3(32, 16, ns), 256, 0, stream>>>(Qb, Kb, Vt, At, Opart, MLpart, 2048 / ns, ns);
        combine_kernel<<<dim3(2048), 256, 0, stream>>>(Opart, MLpart, At, ns);
    } else {
        flash_kernel<<<dim3(32, 16, 1), 256, 0, stream>>>(Qb, Kb, Vt, At, nullptr, nullptr, 2048, 1);
    }

    if (haveWb) {
        wconv_kernel<<<dim3(256), 256, 0, stream>>>(Wfc, (u16*)Wb);
        fc_kernel<<<dim3(64, 8), 256, 0, stream>>>(At, Wb, bfc, out);
    } else {
        fc_f32w_kernel<<<dim3(64, 8), 256, 0, stream>>>(At, Wfc, bfc, out);
    }
}

// Round 5
// 238.705 us; speedup vs baseline: 1.0621x; 1.0621x over previous
//
#include <hip/hip_runtime.h>

// MultiHeadAttention: S=2048, B=2, EMB=512, H=8, D=64 -> 16 independent (b,h)
// groups of [2048 x 64] attention, plus per-head 64x64 QKV projections and a
// 512x512 output FC. All matmuls in bf16 MFMA (16x16x32), fp32 accumulate.
//
// R5: flash is dependency-chain bound (R4 proved not TLP). Fixed softmax
// bound m_q = ||Q_q|| * max_k ||K_k|| (Cauchy-Schwarz) removes the running
// max, alpha, o-rescale and both in-loop shuffle reductions; inner loop is
// QK -> exp2 -> LDS -> PV only, 2 independent 32-key sub-tiles per iter.
//
// ws: [0)   Qb 32768x64 bf16 (pre-scaled by 0.125*log2e)
//     [4M)  Kb 32768x64 bf16
//     [8M)  Vt [16][64][2048] bf16
//     [12M) At 32768x64 bf16
//     [16M) Wb 512x512 bf16
//     [16M+512K) MK[16] float  (per-group max K-row norm)

typedef __attribute__((ext_vector_type(8))) __bf16 bf16x8;
typedef __attribute__((ext_vector_type(4))) float f32x4;
typedef __attribute__((ext_vector_type(4))) unsigned short u16x4;
typedef __attribute__((ext_vector_type(4))) unsigned int u32x4;
typedef unsigned short u16;
typedef unsigned int u32;

static __device__ __forceinline__ u16 f2bf(float x) {
    u32 u = __float_as_uint(x);
    u += 0x7fff + ((u >> 16) & 1);   // RNE
    return (u16)(u >> 16);
}
static __device__ __forceinline__ float bf2f(u16 h) {
    return __uint_as_float(((u32)h) << 16);
}
static __device__ __forceinline__ u32 pack2bf(float lo, float hi) {
    u32 a = __float_as_uint(lo), b = __float_as_uint(hi);
    a += 0x7fff + ((a >> 16) & 1);
    b += 0x7fff + ((b >> 16) & 1);
    return (a >> 16) | (b & 0xffff0000u);
}
static __device__ __forceinline__ bf16x8 pack8(float4 a, float4 b) {
    u32x4 r = { pack2bf(a.x, a.y), pack2bf(a.z, a.w),
                pack2bf(b.x, b.y), pack2bf(b.z, b.w) };
    union { u32x4 u; bf16x8 h; } cvt; cvt.u = r; return cvt.h;
}

// ---------------------------------------------------------------------------
// Kernel 1: QKV projection.  Y = (X @ W^T) * scale, X flat [32768 x 64].
// mode 0 -> Qb (scale 0.125*log2e), 1 -> Kb, 2 -> Vt (transposed in group).
// ---------------------------------------------------------------------------
__global__ __launch_bounds__(256) void proj_kernel(
    const float* __restrict__ q, const float* __restrict__ k, const float* __restrict__ v,
    const float* __restrict__ Wq, const float* __restrict__ Wk, const float* __restrict__ Wv,
    u16* __restrict__ Qb, u16* __restrict__ Kb, u16* __restrict__ Vt)
{
    const int mode = blockIdx.z;
    const float* A = (mode == 0) ? q : (mode == 1) ? k : v;
    const float* W = (mode == 0) ? Wq : (mode == 1) ? Wk : Wv;
    const float osc = (mode == 0) ? 0.18033688011112042f : 1.0f; // 0.125*log2(e)

    __shared__ alignas(16) u16 Ssh[128 * 136];

    const int t = threadIdx.x;
    const int m0 = blockIdx.x * 128;
    const int w = t >> 6, l = t & 63;
    const int r16 = l & 15, q4 = l >> 4;

    bf16x8 af[2][2], wf[4][2];
    #pragma unroll
    for (int mc = 0; mc < 2; ++mc)
        #pragma unroll
        for (int kk = 0; kk < 2; ++kk) {
            const float* p = A + (size_t)(m0 + w * 32 + mc * 16 + r16) * 64 + kk * 32 + q4 * 8;
            af[mc][kk] = pack8(*(const float4*)p, *(const float4*)(p + 4));
        }
    #pragma unroll
    for (int nc = 0; nc < 4; ++nc)
        #pragma unroll
        for (int kk = 0; kk < 2; ++kk) {
            const float* p = W + (size_t)(nc * 16 + r16) * 64 + kk * 32 + q4 * 8;
            wf[nc][kk] = pack8(*(const float4*)p, *(const float4*)(p + 4));
        }

    f32x4 acc[2][4];
    const f32x4 zero = {0.f, 0.f, 0.f, 0.f};
    #pragma unroll
    for (int mc = 0; mc < 2; ++mc)
        #pragma unroll
        for (int nc = 0; nc < 4; ++nc) {
            acc[mc][nc] = zero;
            acc[mc][nc] = __builtin_amdgcn_mfma_f32_16x16x32_bf16(af[mc][0], wf[nc][0], acc[mc][nc], 0, 0, 0);
            acc[mc][nc] = __builtin_amdgcn_mfma_f32_16x16x32_bf16(af[mc][1], wf[nc][1], acc[mc][nc], 0, 0, 0);
        }

    // C/D layout: col(n) = lane&15, row(m) = quad*4 + reg
    if (mode < 2) {
        #pragma unroll
        for (int mc = 0; mc < 2; ++mc)
            #pragma unroll
            for (int nc = 0; nc < 4; ++nc)
                #pragma unroll
                for (int r = 0; r < 4; ++r)
                    Ssh[(w * 32 + mc * 16 + q4 * 4 + r) * 72 + nc * 16 + r16] = f2bf(acc[mc][nc][r] * osc);
        __syncthreads();
        u16* Out = ((mode == 0) ? Qb : Kb) + (size_t)m0 * 64;
        int row = t >> 1, cbase = (t & 1) * 32;
        #pragma unroll
        for (int i = 0; i < 4; ++i)
            *(u32x4*)(Out + row * 64 + cbase + i * 8) = *(const u32x4*)(Ssh + row * 72 + cbase + i * 8);
    } else {
        #pragma unroll
        for (int mc = 0; mc < 2; ++mc)
            #pragma unroll
            for (int nc = 0; nc < 4; ++nc)
                #pragma unroll
                for (int r = 0; r < 4; ++r)
                    Ssh[(nc * 16 + r16) * 136 + w * 32 + mc * 16 + q4 * 4 + r] = f2bf(acc[mc][nc][r]);
        __syncthreads();
        const int g = m0 >> 11, s0 = m0 & 2047;
        int d = t >> 2, sb = (t & 3) * 32;
        u16* Out = Vt + ((size_t)(g * 64 + d)) * 2048 + s0;
        #pragma unroll
        for (int i = 0; i < 4; ++i)
            *(u32x4*)(Out + sb + i * 8) = *(const u32x4*)(Ssh + d * 136 + sb + i * 8);
    }
}

// ---------------------------------------------------------------------------
// Kernel 1b: per-group max K-row norm.  Grid 16 blocks; block g scans its
// 2048 Kb rows (bf16), MK[g] = max_k ||K_k||.
// ---------------------------------------------------------------------------
__global__ __launch_bounds__(256) void knorm_kernel(
    const u16* __restrict__ Kb, float* __restrict__ MK)
{
    const int g = blockIdx.x, t = threadIdx.x;
    __shared__ float red[256];
    float mx = 0.f;
    for (int i = 0; i < 8; ++i) {
        const u16* row = Kb + ((size_t)(g * 2048 + t + i * 256)) * 64;
        float ss = 0.f;
        #pragma unroll
        for (int c = 0; c < 8; ++c) {
            u32x4 d = *(const u32x4*)(row + c * 8);
            #pragma unroll
            for (int j = 0; j < 4; ++j) {
                float lo = bf2f((u16)(d[j] & 0xffff));
                float hi = bf2f((u16)(d[j] >> 16));
                ss += lo * lo + hi * hi;
            }
        }
        mx = fmaxf(mx, ss);
    }
    red[t] = mx;
    __syncthreads();
    for (int s = 128; s > 0; s >>= 1) {
        if (t < s) red[t] = fmaxf(red[t], red[t + s]);
        __syncthreads();
    }
    if (t == 0) MK[g] = sqrtf(red[0]);
}

// ---------------------------------------------------------------------------
// Kernel 2: flash attention, S^T orientation, FIXED softmax bound.
// m = ||Qb_row|| * MK[g] * margin  (Qb pre-scaled, so m is in exp2 domain).
// No running max -> no in-loop shuffles/rescale.  2 independent 32-key
// sub-tiles per iteration (64 keys/iter, 32 iters).  No block barriers.
// ---------------------------------------------------------------------------
__global__ __launch_bounds__(256, 2) void flash_kernel(
    const u16* __restrict__ Qb, const u16* __restrict__ Kb,
    const u16* __restrict__ Vt, const float* __restrict__ MK,
    u16* __restrict__ Att)
{
    const int g = blockIdx.y;    // 0..15
    const int qt = blockIdx.x;   // 0..31
    const int t = threadIdx.x, w = t >> 6, l = t & 63;
    const int r16 = l & 15, q4 = l >> 4;

    __shared__ alignas(16) u16 Psh[4][2][16 * 40];  // [wave][chain][q=16][key=32 pad 40]

    const u16* Kg = Kb + ((size_t)g) * 2048 * 64;
    const u16* Vg = Vt + ((size_t)g) * 64 * 2048;

    // Q B-frag: B[n=q][k=d], lane n=r16, k=q4*8+j (+32)
    bf16x8 qb[2];
    {
        const u16* qp = Qb + ((size_t)(g * 2048 + qt * 64 + w * 16 + r16)) * 64 + q4 * 8;
        qb[0] = *(const bf16x8*)qp;
        qb[1] = *(const bf16x8*)(qp + 32);
    }

    // fixed bound: m = ||Qb_row|| * MK[g] * margin   (per-lane after shfl)
    float m;
    {
        float ss = 0.f;
        #pragma unroll
        for (int kk = 0; kk < 2; ++kk)
            #pragma unroll
            for (int j = 0; j < 8; ++j) {
                float x = (float)qb[kk][j];
                ss += x * x;
            }
        ss += __shfl_xor(ss, 16);
        ss += __shfl_xor(ss, 32);
        m = sqrtf(ss) * MK[g] * 1.0002f;
    }

    f32x4 o[4];
    const f32x4 zero = {0.f, 0.f, 0.f, 0.f};
    #pragma unroll
    for (int dc = 0; dc < 4; ++dc) o[dc] = zero;
    float lsum = 0.f;

    // preload K tile 0, both chains: A[m=key][k=d], lane m=r16
    bf16x8 ka[2][2][2];
    #pragma unroll
    for (int c = 0; c < 2; ++c)
        #pragma unroll
        for (int kc = 0; kc < 2; ++kc) {
            const u16* kp = Kg + ((size_t)(c * 32 + kc * 16 + r16)) * 64 + q4 * 8;
            ka[c][kc][0] = *(const bf16x8*)kp;
            ka[c][kc][1] = *(const bf16x8*)(kp + 32);
        }

    u16* pw[2] = { &Psh[w][0][r16 * 40], &Psh[w][1][r16 * 40] };

    for (int it = 0; it < 32; ++it) {
        // V^T A-frags: A[m=d][k=key], lane m=r16; chains at key +0 / +32
        bf16x8 va[2][4];
        #pragma unroll
        for (int c = 0; c < 2; ++c)
            #pragma unroll
            for (int dc = 0; dc < 4; ++dc)
                va[c][dc] = *(const bf16x8*)(Vg + ((size_t)(dc * 16 + r16)) * 2048
                                             + it * 64 + c * 32 + q4 * 8);

        // S^T = K.Q^T : lane holds q-col r16, keys kc*16 + q4*4 + r
        f32x4 s[2][2];
        #pragma unroll
        for (int c = 0; c < 2; ++c)
            #pragma unroll
            for (int kc = 0; kc < 2; ++kc) {
                s[c][kc] = zero;
                s[c][kc] = __builtin_amdgcn_mfma_f32_16x16x32_bf16(ka[c][kc][0], qb[0], s[c][kc], 0, 0, 0);
                s[c][kc] = __builtin_amdgcn_mfma_f32_16x16x32_bf16(ka[c][kc][1], qb[1], s[c][kc], 0, 0, 0);
            }

        // prefetch next iteration's K tiles
        const int itn = (it + 1) & 31;
        bf16x8 kn[2][2][2];
        #pragma unroll
        for (int c = 0; c < 2; ++c)
            #pragma unroll
            for (int kc = 0; kc < 2; ++kc) {
                const u16* kp = Kg + ((size_t)(itn * 64 + c * 32 + kc * 16 + r16)) * 64 + q4 * 8;
                kn[c][kc][0] = *(const bf16x8*)kp;
                kn[c][kc][1] = *(const bf16x8*)(kp + 32);
            }

        // p = exp2(s - m); accumulate per-lane lsum; no max, no rescale
        float p[2][2][4];
        float psum = 0.f;
        #pragma unroll
        for (int c = 0; c < 2; ++c)
            #pragma unroll
            for (int kc = 0; kc < 2; ++kc)
                #pragma unroll
                for (int r = 0; r < 4; ++r) {
                    p[c][kc][r] = exp2f(s[c][kc][r] - m);
                    psum += p[c][kc][r];
                }
        lsum += psum;

        // P^T (C-layout) -> per-wave LDS -> B-frag, both chains
        #pragma unroll
        for (int c = 0; c < 2; ++c)
            #pragma unroll
            for (int kc = 0; kc < 2; ++kc) {
                uint2 dd = { pack2bf(p[c][kc][0], p[c][kc][1]),
                             pack2bf(p[c][kc][2], p[c][kc][3]) };
                *(uint2*)(pw[c] + kc * 16 + q4 * 4) = dd;
            }
        #pragma unroll
        for (int c = 0; c < 2; ++c) {
            bf16x8 pb = *(const bf16x8*)(pw[c] + q4 * 8);  // B[n=q=r16][k=key]
            #pragma unroll
            for (int dc = 0; dc < 4; ++dc)
                o[dc] = __builtin_amdgcn_mfma_f32_16x16x32_bf16(va[c][dc], pb, o[dc], 0, 0, 0);
        }

        #pragma unroll
        for (int c = 0; c < 2; ++c)
            #pragma unroll
            for (int kc = 0; kc < 2; ++kc) {
                ka[c][kc][0] = kn[c][kc][0];
                ka[c][kc][1] = kn[c][kc][1];
            }
    }

    // epilogue: complete lsum across q4 groups, normalize, store
    float lt = lsum;
    lt += __shfl_xor(lt, 16);
    lt += __shfl_xor(lt, 32);
    float inv = 1.0f / lt;
    const int qq = qt * 64 + w * 16 + r16;
    u16* orow = Att + ((size_t)(g * 2048 + qq)) * 64;
    #pragma unroll
    for (int dc = 0; dc < 4; ++dc) {
        u16x4 bb = { f2bf(o[dc][0] * inv), f2bf(o[dc][1] * inv),
                     f2bf(o[dc][2] * inv), f2bf(o[dc][3] * inv) };
        *(u16x4*)(orow + dc * 16 + q4 * 4) = bb;
    }
}

// ---------------------------------------------------------------------------
// Kernel 3a: Wfc fp32 -> bf16 (512 KiB, L2-resident for fc).
// ---------------------------------------------------------------------------
__global__ __launch_bounds__(256) void wconv_kernel(
    const float* __restrict__ Wfc, u16* __restrict__ Wb)
{
    int i = (blockIdx.x * 256 + threadIdx.x) * 4;
    float4 v = *(const float4*)(Wfc + i);
    u16x4 b = { f2bf(v.x), f2bf(v.y), f2bf(v.z), f2bf(v.w) };
    *(u16x4*)(Wb + i) = b;
}

// ---------------------------------------------------------------------------
// Kernel 3b: out = Att @ Wb^T + bfc.  Zero LDS/barriers.  Grid (64,8).
// ---------------------------------------------------------------------------
__global__ __launch_bounds__(256) void fc_kernel(
    const u16* __restrict__ Att, const u16* __restrict__ Wb,
    const float* __restrict__ bfc, float* __restrict__ out)
{
    const int t = threadIdx.x, w = t >> 6, l = t & 63;
    const int r16 = l & 15, q4 = l >> 4;
    const int m0 = blockIdx.x * 64, n0 = blockIdx.y * 64;

    const u16* arow = Att + (size_t)(m0 + w * 16 + r16) * 512 + q4 * 8;

    f32x4 acc[4];
    const f32x4 zero = {0.f, 0.f, 0.f, 0.f};
    #pragma unroll
    for (int nc = 0; nc < 4; ++nc) acc[nc] = zero;

    #pragma unroll 2
    for (int k0 = 0; k0 < 512; k0 += 64) {
        bf16x8 af[2], wf[4][2];
        #pragma unroll
        for (int kk = 0; kk < 2; ++kk)
            af[kk] = *(const bf16x8*)(arow + k0 + kk * 32);
        #pragma unroll
        for (int nc = 0; nc < 4; ++nc)
            #pragma unroll
            for (int kk = 0; kk < 2; ++kk)
                wf[nc][kk] = *(const bf16x8*)(Wb + (size_t)(n0 + nc * 16 + r16) * 512
                                              + k0 + kk * 32 + q4 * 8);
        #pragma unroll
        for (int nc = 0; nc < 4; ++nc) {
            acc[nc] = __builtin_amdgcn_mfma_f32_16x16x32_bf16(af[0], wf[nc][0], acc[nc], 0, 0, 0);
            acc[nc] = __builtin_amdgcn_mfma_f32_16x16x32_bf16(af[1], wf[nc][1], acc[nc], 0, 0, 0);
        }
    }

    #pragma unroll
    for (int nc = 0; nc < 4; ++nc) {
        float bb = bfc[n0 + nc * 16 + r16];
        #pragma unroll
        for (int r = 0; r < 4; ++r) {
            int row = m0 + w * 16 + q4 * 4 + r;
            out[(size_t)row * 512 + n0 + nc * 16 + r16] = acc[nc][r] + bb;
        }
    }
}

// Fallback fc when ws can't hold Wb: pack W from fp32 in-register.
__global__ __launch_bounds__(256) void fc_f32w_kernel(
    const u16* __restrict__ Att, const float* __restrict__ Wfc,
    const float* __restrict__ bfc, float* __restrict__ out)
{
    const int t = threadIdx.x, w = t >> 6, l = t & 63;
    const int r16 = l & 15, q4 = l >> 4;
    const int m0 = blockIdx.x * 64, n0 = blockIdx.y * 64;
    const u16* arow = Att + (size_t)(m0 + w * 16 + r16) * 512 + q4 * 8;
    f32x4 acc[4];
    const f32x4 zero = {0.f, 0.f, 0.f, 0.f};
    #pragma unroll
    for (int nc = 0; nc < 4; ++nc) acc[nc] = zero;
    for (int k0 = 0; k0 < 512; k0 += 64) {
        bf16x8 af[2], wf[4][2];
        #pragma unroll
        for (int kk = 0; kk < 2; ++kk)
            af[kk] = *(const bf16x8*)(arow + k0 + kk * 32);
        #pragma unroll
        for (int nc = 0; nc < 4; ++nc)
            #pragma unroll
            for (int kk = 0; kk < 2; ++kk) {
                const float* p = Wfc + (size_t)(n0 + nc * 16 + r16) * 512 + k0 + kk * 32 + q4 * 8;
                wf[nc][kk] = pack8(*(const float4*)p, *(const float4*)(p + 4));
            }
        #pragma unroll
        for (int nc = 0; nc < 4; ++nc) {
            acc[nc] = __builtin_amdgcn_mfma_f32_16x16x32_bf16(af[0], wf[nc][0], acc[nc], 0, 0, 0);
            acc[nc] = __builtin_amdgcn_mfma_f32_16x16x32_bf16(af[1], wf[nc][1], acc[nc], 0, 0, 0);
        }
    }
    #pragma unroll
    for (int nc = 0; nc < 4; ++nc) {
        float bb = bfc[n0 + nc * 16 + r16];
        #pragma unroll
        for (int r = 0; r < 4; ++r) {
            int row = m0 + w * 16 + q4 * 4 + r;
            out[(size_t)row * 512 + n0 + nc * 16 + r16] = acc[nc][r] + bb;
        }
    }
}

extern "C" void kernel_launch(void* const* d_in, const int* in_sizes, int n_in,
                              void* d_out, int out_size, void* d_ws, size_t ws_size,
                              hipStream_t stream) {
    (void)in_sizes; (void)n_in; (void)out_size;
    const float* q   = (const float*)d_in[0];
    const float* k   = (const float*)d_in[1];
    const float* v   = (const float*)d_in[2];
    const float* Wq  = (const float*)d_in[3];
    const float* Wk  = (const float*)d_in[4];
    const float* Wv  = (const float*)d_in[5];
    const float* Wfc = (const float*)d_in[6];
    const float* bfc = (const float*)d_in[7];
    float* out = (float*)d_out;

    u16* Qb = (u16*)d_ws;
    u16* Kb = Qb + 2097152;
    u16* Vt = Kb + 2097152;
    u16* At = Vt + 2097152;
    u16* Wb = At + 2097152;                    // [16M, 16M+512K)
    float* MKp = (float*)((char*)d_ws + 17301504);   // 16 floats
    bool haveWb = ws_size >= 17301504 + 64;

    proj_kernel<<<dim3(256, 1, 3), 256, 0, stream>>>(q, k, v, Wq, Wk, Wv, Qb, Kb, Vt);
    knorm_kernel<<<dim3(16), 256, 0, stream>>>(Kb, MKp);
    flash_kernel<<<dim3(32, 16), 256, 0, stream>>>(Qb, Kb, Vt, MKp, At);

    if (haveWb) {
        wconv_kernel<<<dim3(256), 256, 0, stream>>>(Wfc, Wb);
        fc_kernel<<<dim3(64, 8), 256, 0, stream>>>(At, Wb, bfc, out);
    } else {
        fc_f32w_kernel<<<dim3(64, 8), 256, 0, stream>>>(At, Wfc, bfc, out);
    }
}

// Round 6
// 152.012 us; speedup vs baseline: 1.6678x; 1.5703x over previous
//
#include <hip/hip_runtime.h>

// MultiHeadAttention: S=2048, B=2, EMB=512, H=8, D=64 -> 16 (b,h) groups of
// [2048 x 64] attention + per-head 64x64 QKV proj + 512x512 output FC.
// All matmuls bf16 MFMA 16x16x32, fp32 accumulate.
//
// R6: R2-R5 flash was bound by strided global fragment loads (16-line txn
// split per load). Now: coalesced staging of K/V tiles into double-buffered
// LDS (1 barrier/iter), ds_read_b128 fragments, register prefetch, fixed
// softmax bound (R5). 3 dispatches total: proj(+wconv+knorm), flash, fc.
//
// ws: [0)   Qb 32768x64 bf16 (pre-scaled by 0.125*log2e)
//     [4M)  Kb 32768x64 bf16
//     [8M)  Vt [16][64][2048] bf16
//     [12M) At 32768x64 bf16
//     [16M) Wb 512x512 bf16
//     [16M+512K) KnSq[256] float (per-128-row-block max ||K row||^2)

typedef __attribute__((ext_vector_type(8))) __bf16 bf16x8;
typedef __attribute__((ext_vector_type(4))) float f32x4;
typedef __attribute__((ext_vector_type(4))) unsigned short u16x4;
typedef __attribute__((ext_vector_type(4))) unsigned int u32x4;
typedef unsigned short u16;
typedef unsigned int u32;

static __device__ __forceinline__ u16 f2bf(float x) {
    u32 u = __float_as_uint(x);
    u += 0x7fff + ((u >> 16) & 1);   // RNE
    return (u16)(u >> 16);
}
static __device__ __forceinline__ float bf2f(u16 h) {
    return __uint_as_float(((u32)h) << 16);
}
static __device__ __forceinline__ u32 pack2bf(float lo, float hi) {
    u32 a = __float_as_uint(lo), b = __float_as_uint(hi);
    a += 0x7fff + ((a >> 16) & 1);
    b += 0x7fff + ((b >> 16) & 1);
    return (a >> 16) | (b & 0xffff0000u);
}

// ---------------------------------------------------------------------------
// Kernel 1: z=0/1/2 -> QKV projection (Y = X@W^T * scale), z=3 -> Wfc->bf16.
// LDS-staged (coalesced loads), MFMA, LDS-staged coalesced stores.
// z=1 (K) additionally writes per-block max row-norm^2 to KnSq[bx].
// ---------------------------------------------------------------------------
__global__ __launch_bounds__(256) void proj_kernel(
    const float* __restrict__ q, const float* __restrict__ k, const float* __restrict__ v,
    const float* __restrict__ Wq, const float* __restrict__ Wk, const float* __restrict__ Wv,
    const float* __restrict__ Wfc,
    u16* __restrict__ Qb, u16* __restrict__ Kb, u16* __restrict__ Vt,
    u16* __restrict__ Wb, float* __restrict__ KnSq)
{
    const int mode = blockIdx.z;
    const int t = threadIdx.x;

    if (mode == 3) {   // Wfc fp32 -> bf16, fully coalesced
        int i = (blockIdx.x * 256 + t) * 4;
        float4 val = *(const float4*)(Wfc + i);
        u16x4 b = { f2bf(val.x), f2bf(val.y), f2bf(val.z), f2bf(val.w) };
        *(u16x4*)(Wb + i) = b;
        return;
    }

    const float* A = (mode == 0) ? q : (mode == 1) ? k : v;
    const float* W = (mode == 0) ? Wq : (mode == 1) ? Wk : Wv;
    const float osc = (mode == 0) ? 0.18033688011112042f : 1.0f; // 0.125*log2(e)

    __shared__ alignas(16) u16 Ash[128 * 88];   // input stage, reused for output
    __shared__ alignas(16) u16 Wsh[64 * 88];
    __shared__ float red[128];

    const int m0 = blockIdx.x * 128;
    const int w = t >> 6, l = t & 63;
    const int r16 = l & 15, q4 = l >> 4;

    {   // stage A tile 128x64 fp32->bf16 (coalesced float4)
        const float4* A4 = (const float4*)(A + (size_t)m0 * 64);
        const int c4 = t & 15;
        #pragma unroll
        for (int i = 0; i < 8; ++i) {
            int row = (t >> 4) + i * 16;
            float4 val = A4[row * 16 + c4];
            u16x4 bb = { f2bf(val.x), f2bf(val.y), f2bf(val.z), f2bf(val.w) };
            *(u16x4*)(Ash + row * 88 + c4 * 4) = bb;
        }
        const float4* W4 = (const float4*)W;
        #pragma unroll
        for (int i = 0; i < 4; ++i) {
            int row = (t >> 4) + i * 16;
            float4 val = W4[row * 16 + c4];
            u16x4 bb = { f2bf(val.x), f2bf(val.y), f2bf(val.z), f2bf(val.w) };
            *(u16x4*)(Wsh + row * 88 + c4 * 4) = bb;
        }
    }
    __syncthreads();

    bf16x8 af[2][2], wf[4][2];
    #pragma unroll
    for (int mc = 0; mc < 2; ++mc)
        #pragma unroll
        for (int kk = 0; kk < 2; ++kk)
            af[mc][kk] = *(const bf16x8*)(Ash + (w * 32 + mc * 16 + r16) * 88 + kk * 32 + q4 * 8);
    #pragma unroll
    for (int nc = 0; nc < 4; ++nc)
        #pragma unroll
        for (int kk = 0; kk < 2; ++kk)
            wf[nc][kk] = *(const bf16x8*)(Wsh + (nc * 16 + r16) * 88 + kk * 32 + q4 * 8);

    f32x4 acc[2][4];
    const f32x4 zero = {0.f, 0.f, 0.f, 0.f};
    #pragma unroll
    for (int mc = 0; mc < 2; ++mc)
        #pragma unroll
        for (int nc = 0; nc < 4; ++nc) {
            acc[mc][nc] = zero;
            acc[mc][nc] = __builtin_amdgcn_mfma_f32_16x16x32_bf16(af[mc][0], wf[nc][0], acc[mc][nc], 0, 0, 0);
            acc[mc][nc] = __builtin_amdgcn_mfma_f32_16x16x32_bf16(af[mc][1], wf[nc][1], acc[mc][nc], 0, 0, 0);
        }

    __syncthreads();   // done reading Ash/Wsh; reuse Ash as output stage

    // C/D layout: col(n) = lane&15, row(m) = quad*4 + reg
    if (mode < 2) {
        #pragma unroll
        for (int mc = 0; mc < 2; ++mc)
            #pragma unroll
            for (int nc = 0; nc < 4; ++nc)
                #pragma unroll
                for (int r = 0; r < 4; ++r)
                    Ash[(w * 32 + mc * 16 + q4 * 4 + r) * 72 + nc * 16 + r16] = f2bf(acc[mc][nc][r] * osc);
        __syncthreads();
        u16* Out = ((mode == 0) ? Qb : Kb) + (size_t)m0 * 64;
        {
            int row = t >> 1, cbase = (t & 1) * 32;
            #pragma unroll
            for (int i = 0; i < 4; ++i)
                *(u32x4*)(Out + row * 64 + cbase + i * 8) = *(const u32x4*)(Ash + row * 72 + cbase + i * 8);
        }
        if (mode == 1) {   // per-block max ||K row||^2 from stored bf16 values
            if (t < 128) {
                float ss = 0.f;
                #pragma unroll
                for (int c = 0; c < 8; ++c) {
                    u32x4 d = *(const u32x4*)(Ash + t * 72 + c * 8);
                    #pragma unroll
                    for (int j = 0; j < 4; ++j) {
                        float lo = bf2f((u16)(d[j] & 0xffff));
                        float hi = bf2f((u16)(d[j] >> 16));
                        ss += lo * lo + hi * hi;
                    }
                }
                red[t] = ss;
            }
            __syncthreads();
            if (t < 64) red[t] = fmaxf(red[t], red[t + 64]);
            __syncthreads();
            if (t < 32) red[t] = fmaxf(red[t], red[t + 32]);
            __syncthreads();
            if (t == 0) {
                float mx = red[0];
                for (int i = 1; i < 32; ++i) mx = fmaxf(mx, red[i]);
                KnSq[blockIdx.x] = mx;     // bx = g*16 + j
            }
        }
    } else {
        #pragma unroll
        for (int mc = 0; mc < 2; ++mc)
            #pragma unroll
            for (int nc = 0; nc < 4; ++nc)
                #pragma unroll
                for (int r = 0; r < 4; ++r)
                    Ash[(nc * 16 + r16) * 136 + w * 32 + mc * 16 + q4 * 4 + r] = f2bf(acc[mc][nc][r]);
        __syncthreads();
        const int g = m0 >> 11, s0 = m0 & 2047;
        int d = t >> 2, sb = (t & 3) * 32;
        u16* Out = Vt + ((size_t)(g * 64 + d)) * 2048 + s0;
        #pragma unroll
        for (int i = 0; i < 4; ++i)
            *(u32x4*)(Out + sb + i * 8) = *(const u32x4*)(Ash + d * 136 + sb + i * 8);
    }
}

// ---------------------------------------------------------------------------
// Kernel 2: flash attention, S^T orientation, fixed softmax bound, LDS
// double-buffered K/V tiles (64 keys/iter, 32 iters, 1 barrier/iter).
// Staging loads fully coalesced; fragments via ds_read_b128 (pad 72).
// ---------------------------------------------------------------------------
__global__ __launch_bounds__(256) void flash_kernel(
    const u16* __restrict__ Qb, const u16* __restrict__ Kb,
    const u16* __restrict__ Vt, const float* __restrict__ KnSq,
    u16* __restrict__ Att)
{
    const int g = blockIdx.y;    // 0..15
    const int qt = blockIdx.x;   // 0..31
    const int t = threadIdx.x, w = t >> 6, l = t & 63;
    const int r16 = l & 15, q4 = l >> 4;

    __shared__ alignas(16) u16 Kt[2][64 * 72];   // [buf][key][d pad 72]
    __shared__ alignas(16) u16 Vs[2][64 * 72];   // [buf][d][key pad 72]
    __shared__ alignas(16) u16 Psh[4][16 * 72];  // per-wave P^T [q][key pad 72]

    const u16* Kg = Kb + ((size_t)g) * 2048 * 64;
    const u16* Vg = Vt + ((size_t)g) * 64 * 2048;

    // Q B-frag: B[n=q][k=d], lane n=r16, k=q4*8+j (+32)
    bf16x8 qb[2];
    {
        const u16* qp = Qb + ((size_t)(g * 2048 + qt * 64 + w * 16 + r16)) * 64 + q4 * 8;
        qb[0] = *(const bf16x8*)qp;
        qb[1] = *(const bf16x8*)(qp + 32);
    }

    // fixed bound m = ||Qrow_scaled|| * max_k||K_k|| * margin
    float m;
    {
        float kss = KnSq[g * 16 + r16];
        kss = fmaxf(kss, __shfl_xor(kss, 1));
        kss = fmaxf(kss, __shfl_xor(kss, 2));
        kss = fmaxf(kss, __shfl_xor(kss, 4));
        kss = fmaxf(kss, __shfl_xor(kss, 8));
        float ss = 0.f;
        #pragma unroll
        for (int kk = 0; kk < 2; ++kk)
            #pragma unroll
            for (int j = 0; j < 8; ++j) {
                float x = (float)qb[kk][j];
                ss += x * x;
            }
        ss += __shfl_xor(ss, 16);
        ss += __shfl_xor(ss, 32);
        m = sqrtf(ss) * sqrtf(kss) * 1.0002f;
    }

    // coalesced staging mapping: thread t covers (row = h*32 + t>>3, chunk = t&7)
    const int rr = t >> 3, ck = t & 7;

    {   // stage tile 0 into buf 0
        #pragma unroll
        for (int h = 0; h < 2; ++h) {
            int row = h * 32 + rr;
            *(u32x4*)(&Kt[0][row * 72 + ck * 8]) = *(const u32x4*)(Kg + (size_t)row * 64 + ck * 8);
            *(u32x4*)(&Vs[0][row * 72 + ck * 8]) = *(const u32x4*)(Vg + (size_t)row * 2048 + ck * 8);
        }
    }
    __syncthreads();

    f32x4 o[4];
    const f32x4 zero = {0.f, 0.f, 0.f, 0.f};
    #pragma unroll
    for (int dc = 0; dc < 4; ++dc) o[dc] = zero;
    float lsum = 0.f;

    u16* pw = &Psh[w][r16 * 72];

    for (int it = 0; it < 32; ++it) {
        const int cur = it & 1;
        const bool hasn = (it < 31);

        // register prefetch of next tile (coalesced)
        u32x4 knx[2], vnx[2];
        if (hasn) {
            #pragma unroll
            for (int h = 0; h < 2; ++h) {
                int row = h * 32 + rr;
                knx[h] = *(const u32x4*)(Kg + (size_t)((it + 1) * 64 + row) * 64 + ck * 8);
                vnx[h] = *(const u32x4*)(Vg + (size_t)row * 2048 + (it + 1) * 64 + ck * 8);
            }
        }

        // fragments from LDS
        const u16* Kc = Kt[cur];
        const u16* Vc = Vs[cur];
        bf16x8 ka[4][2], va[4][2];
        #pragma unroll
        for (int kc = 0; kc < 4; ++kc)
            #pragma unroll
            for (int kk = 0; kk < 2; ++kk)
                ka[kc][kk] = *(const bf16x8*)(Kc + (kc * 16 + r16) * 72 + kk * 32 + q4 * 8);
        #pragma unroll
        for (int dc = 0; dc < 4; ++dc)
            #pragma unroll
            for (int kk = 0; kk < 2; ++kk)
                va[dc][kk] = *(const bf16x8*)(Vc + (dc * 16 + r16) * 72 + kk * 32 + q4 * 8);

        // S^T = K.Q^T : lane holds q-col r16, keys kc*16 + q4*4 + r
        f32x4 s[4];
        #pragma unroll
        for (int kc = 0; kc < 4; ++kc) {
            s[kc] = zero;
            s[kc] = __builtin_amdgcn_mfma_f32_16x16x32_bf16(ka[kc][0], qb[0], s[kc], 0, 0, 0);
            s[kc] = __builtin_amdgcn_mfma_f32_16x16x32_bf16(ka[kc][1], qb[1], s[kc], 0, 0, 0);
        }

        // p = exp2(s - m); per-lane lsum (no reductions, no rescale)
        float p[4][4];
        float psum = 0.f;
        #pragma unroll
        for (int kc = 0; kc < 4; ++kc)
            #pragma unroll
            for (int r = 0; r < 4; ++r) {
                p[kc][r] = exp2f(s[kc][r] - m);
                psum += p[kc][r];
            }
        lsum += psum;

        // P^T (C-layout) -> per-wave LDS row q=r16 -> B-frag
        #pragma unroll
        for (int kc = 0; kc < 4; ++kc) {
            uint2 dd = { pack2bf(p[kc][0], p[kc][1]), pack2bf(p[kc][2], p[kc][3]) };
            *(uint2*)(pw + kc * 16 + q4 * 4) = dd;
        }
        bf16x8 pb0 = *(const bf16x8*)(pw + q4 * 8);
        bf16x8 pb1 = *(const bf16x8*)(pw + 32 + q4 * 8);

        // O^T += V^T . P^T
        #pragma unroll
        for (int dc = 0; dc < 4; ++dc) {
            o[dc] = __builtin_amdgcn_mfma_f32_16x16x32_bf16(va[dc][0], pb0, o[dc], 0, 0, 0);
            o[dc] = __builtin_amdgcn_mfma_f32_16x16x32_bf16(va[dc][1], pb1, o[dc], 0, 0, 0);
        }

        // stage next tile into buf^1
        if (hasn) {
            const int nxt = cur ^ 1;
            #pragma unroll
            for (int h = 0; h < 2; ++h) {
                int row = h * 32 + rr;
                *(u32x4*)(&Kt[nxt][row * 72 + ck * 8]) = knx[h];
                *(u32x4*)(&Vs[nxt][row * 72 + ck * 8]) = vnx[h];
            }
        }
        __syncthreads();
    }

    // epilogue: complete lsum across q4 groups, normalize, store
    float lt = lsum;
    lt += __shfl_xor(lt, 16);
    lt += __shfl_xor(lt, 32);
    float inv = 1.0f / lt;
    const int qq = qt * 64 + w * 16 + r16;
    u16* orow = Att + ((size_t)(g * 2048 + qq)) * 64;
    #pragma unroll
    for (int dc = 0; dc < 4; ++dc) {
        u16x4 bb = { f2bf(o[dc][0] * inv), f2bf(o[dc][1] * inv),
                     f2bf(o[dc][2] * inv), f2bf(o[dc][3] * inv) };
        *(u16x4*)(orow + dc * 16 + q4 * 4) = bb;
    }
}

// ---------------------------------------------------------------------------
// Kernel 3: out = Att @ Wb^T + bfc (Wb bf16).  Zero LDS/barriers.  Grid (64,8).
// ---------------------------------------------------------------------------
__global__ __launch_bounds__(256) void fc_kernel(
    const u16* __restrict__ Att, const u16* __restrict__ Wb,
    const float* __restrict__ bfc, float* __restrict__ out)
{
    const int t = threadIdx.x, w = t >> 6, l = t & 63;
    const int r16 = l & 15, q4 = l >> 4;
    const int m0 = blockIdx.x * 64, n0 = blockIdx.y * 64;

    const u16* arow = Att + (size_t)(m0 + w * 16 + r16) * 512 + q4 * 8;

    f32x4 acc[4];
    const f32x4 zero = {0.f, 0.f, 0.f, 0.f};
    #pragma unroll
    for (int nc = 0; nc < 4; ++nc) acc[nc] = zero;

    #pragma unroll 2
    for (int k0 = 0; k0 < 512; k0 += 64) {
        bf16x8 af[2], wf[4][2];
        #pragma unroll
        for (int kk = 0; kk < 2; ++kk)
            af[kk] = *(const bf16x8*)(arow + k0 + kk * 32);
        #pragma unroll
        for (int nc = 0; nc < 4; ++nc)
            #pragma unroll
            for (int kk = 0; kk < 2; ++kk)
                wf[nc][kk] = *(const bf16x8*)(Wb + (size_t)(n0 + nc * 16 + r16) * 512
                                              + k0 + kk * 32 + q4 * 8);
        #pragma unroll
        for (int nc = 0; nc < 4; ++nc) {
            acc[nc] = __builtin_amdgcn_mfma_f32_16x16x32_bf16(af[0], wf[nc][0], acc[nc], 0, 0, 0);
            acc[nc] = __builtin_amdgcn_mfma_f32_16x16x32_bf16(af[1], wf[nc][1], acc[nc], 0, 0, 0);
        }
    }

    #pragma unroll
    for (int nc = 0; nc < 4; ++nc) {
        float bb = bfc[n0 + nc * 16 + r16];
        #pragma unroll
        for (int r = 0; r < 4; ++r) {
            int row = m0 + w * 16 + q4 * 4 + r;
            out[(size_t)row * 512 + n0 + nc * 16 + r16] = acc[nc][r] + bb;
        }
    }
}

extern "C" void kernel_launch(void* const* d_in, const int* in_sizes, int n_in,
                              void* d_out, int out_size, void* d_ws, size_t ws_size,
                              hipStream_t stream) {
    (void)in_sizes; (void)n_in; (void)out_size; (void)ws_size;
    const float* q   = (const float*)d_in[0];
    const float* k   = (const float*)d_in[1];
    const float* v   = (const float*)d_in[2];
    const float* Wq  = (const float*)d_in[3];
    const float* Wk  = (const float*)d_in[4];
    const float* Wv  = (const float*)d_in[5];
    const float* Wfc = (const float*)d_in[6];
    const float* bfc = (const float*)d_in[7];
    float* out = (float*)d_out;

    u16* Qb = (u16*)d_ws;
    u16* Kb = Qb + 2097152;
    u16* Vt = Kb + 2097152;
    u16* At = Vt + 2097152;
    u16* Wb = At + 2097152;                         // 512 KiB
    float* KnSq = (float*)((char*)d_ws + 17301504); // 256 floats

    proj_kernel<<<dim3(256, 1, 4), 256, 0, stream>>>(q, k, v, Wq, Wk, Wv, Wfc,
                                                     Qb, Kb, Vt, Wb, KnSq);
    flash_kernel<<<dim3(32, 16), 256, 0, stream>>>(Qb, Kb, Vt, KnSq, At);
    fc_kernel<<<dim3(64, 8), 256, 0, stream>>>(At, Wb, bfc, out);
}

// Round 7
// 135.496 us; speedup vs baseline: 1.8711x; 1.1219x over previous
//
#include <hip/hip_runtime.h>

// MultiHeadAttention: S=2048, B=2, EMB=512, H=8, D=64 -> 16 (b,h) groups of
// [2048 x 64] attention + per-head 64x64 QKV proj + 512x512 output FC.
// All matmuls bf16 MFMA 16x16x32, fp32 accumulate.
//
// R7: fc gets coalesced LDS staging (was 16-line-split strided fragment
// loads); flash+fc LDS tiles use XOR swizzle (chunk ck of row r at ck^(r&7))
// -> conflict-free staging writes, fragment reads, and P round-trip.
//
// ws: [0)   Qb 32768x64 bf16 (pre-scaled by 0.125*log2e)
//     [4M)  Kb 32768x64 bf16
//     [8M)  Vt [16][64][2048] bf16
//     [12M) At 32768x64 bf16
//     [16M) Wb 512x512 bf16
//     [16M+512K) KnSq[256] float (per-128-row-block max ||K row||^2)

typedef __attribute__((ext_vector_type(8))) __bf16 bf16x8;
typedef __attribute__((ext_vector_type(4))) float f32x4;
typedef __attribute__((ext_vector_type(4))) unsigned short u16x4;
typedef __attribute__((ext_vector_type(4))) unsigned int u32x4;
typedef unsigned short u16;
typedef unsigned int u32;

static __device__ __forceinline__ u16 f2bf(float x) {
    u32 u = __float_as_uint(x);
    u += 0x7fff + ((u >> 16) & 1);   // RNE
    return (u16)(u >> 16);
}
static __device__ __forceinline__ float bf2f(u16 h) {
    return __uint_as_float(((u32)h) << 16);
}
static __device__ __forceinline__ u32 pack2bf(float lo, float hi) {
    u32 a = __float_as_uint(lo), b = __float_as_uint(hi);
    a += 0x7fff + ((a >> 16) & 1);
    b += 0x7fff + ((b >> 16) & 1);
    return (a >> 16) | (b & 0xffff0000u);
}

// ---------------------------------------------------------------------------
// Kernel 1: z=0/1/2 -> QKV projection (Y = X@W^T * scale), z=3 -> Wfc->bf16.
// z=1 (K) additionally writes per-block max row-norm^2 to KnSq[bx].
// ---------------------------------------------------------------------------
__global__ __launch_bounds__(256) void proj_kernel(
    const float* __restrict__ q, const float* __restrict__ k, const float* __restrict__ v,
    const float* __restrict__ Wq, const float* __restrict__ Wk, const float* __restrict__ Wv,
    const float* __restrict__ Wfc,
    u16* __restrict__ Qb, u16* __restrict__ Kb, u16* __restrict__ Vt,
    u16* __restrict__ Wb, float* __restrict__ KnSq)
{
    const int mode = blockIdx.z;
    const int t = threadIdx.x;

    if (mode == 3) {   // Wfc fp32 -> bf16, fully coalesced
        int i = (blockIdx.x * 256 + t) * 4;
        float4 val = *(const float4*)(Wfc + i);
        u16x4 b = { f2bf(val.x), f2bf(val.y), f2bf(val.z), f2bf(val.w) };
        *(u16x4*)(Wb + i) = b;
        return;
    }

    const float* A = (mode == 0) ? q : (mode == 1) ? k : v;
    const float* W = (mode == 0) ? Wq : (mode == 1) ? Wk : Wv;
    const float osc = (mode == 0) ? 0.18033688011112042f : 1.0f; // 0.125*log2(e)

    __shared__ alignas(16) u16 Ash[128 * 88];   // input stage, reused for output
    __shared__ alignas(16) u16 Wsh[64 * 88];
    __shared__ float red[128];

    const int m0 = blockIdx.x * 128;
    const int w = t >> 6, l = t & 63;
    const int r16 = l & 15, q4 = l >> 4;

    {   // stage A tile 128x64 fp32->bf16 (coalesced float4)
        const float4* A4 = (const float4*)(A + (size_t)m0 * 64);
        const int c4 = t & 15;
        #pragma unroll
        for (int i = 0; i < 8; ++i) {
            int row = (t >> 4) + i * 16;
            float4 val = A4[row * 16 + c4];
            u16x4 bb = { f2bf(val.x), f2bf(val.y), f2bf(val.z), f2bf(val.w) };
            *(u16x4*)(Ash + row * 88 + c4 * 4) = bb;
        }
        const float4* W4 = (const float4*)W;
        #pragma unroll
        for (int i = 0; i < 4; ++i) {
            int row = (t >> 4) + i * 16;
            float4 val = W4[row * 16 + c4];
            u16x4 bb = { f2bf(val.x), f2bf(val.y), f2bf(val.z), f2bf(val.w) };
            *(u16x4*)(Wsh + row * 88 + c4 * 4) = bb;
        }
    }
    __syncthreads();

    bf16x8 af[2][2], wf[4][2];
    #pragma unroll
    for (int mc = 0; mc < 2; ++mc)
        #pragma unroll
        for (int kk = 0; kk < 2; ++kk)
            af[mc][kk] = *(const bf16x8*)(Ash + (w * 32 + mc * 16 + r16) * 88 + kk * 32 + q4 * 8);
    #pragma unroll
    for (int nc = 0; nc < 4; ++nc)
        #pragma unroll
        for (int kk = 0; kk < 2; ++kk)
            wf[nc][kk] = *(const bf16x8*)(Wsh + (nc * 16 + r16) * 88 + kk * 32 + q4 * 8);

    f32x4 acc[2][4];
    const f32x4 zero = {0.f, 0.f, 0.f, 0.f};
    #pragma unroll
    for (int mc = 0; mc < 2; ++mc)
        #pragma unroll
        for (int nc = 0; nc < 4; ++nc) {
            acc[mc][nc] = zero;
            acc[mc][nc] = __builtin_amdgcn_mfma_f32_16x16x32_bf16(af[mc][0], wf[nc][0], acc[mc][nc], 0, 0, 0);
            acc[mc][nc] = __builtin_amdgcn_mfma_f32_16x16x32_bf16(af[mc][1], wf[nc][1], acc[mc][nc], 0, 0, 0);
        }

    __syncthreads();   // done reading Ash/Wsh; reuse Ash as output stage

    // C/D layout: col(n) = lane&15, row(m) = quad*4 + reg
    if (mode < 2) {
        #pragma unroll
        for (int mc = 0; mc < 2; ++mc)
            #pragma unroll
            for (int nc = 0; nc < 4; ++nc)
                #pragma unroll
                for (int r = 0; r < 4; ++r)
                    Ash[(w * 32 + mc * 16 + q4 * 4 + r) * 72 + nc * 16 + r16] = f2bf(acc[mc][nc][r] * osc);
        __syncthreads();
        u16* Out = ((mode == 0) ? Qb : Kb) + (size_t)m0 * 64;
        {
            int row = t >> 1, cbase = (t & 1) * 32;
            #pragma unroll
            for (int i = 0; i < 4; ++i)
                *(u32x4*)(Out + row * 64 + cbase + i * 8) = *(const u32x4*)(Ash + row * 72 + cbase + i * 8);
        }
        if (mode == 1) {   // per-block max ||K row||^2 from stored bf16 values
            if (t < 128) {
                float ss = 0.f;
                #pragma unroll
                for (int c = 0; c < 8; ++c) {
                    u32x4 d = *(const u32x4*)(Ash + t * 72 + c * 8);
                    #pragma unroll
                    for (int j = 0; j < 4; ++j) {
                        float lo = bf2f((u16)(d[j] & 0xffff));
                        float hi = bf2f((u16)(d[j] >> 16));
                        ss += lo * lo + hi * hi;
                    }
                }
                red[t] = ss;
            }
            __syncthreads();
            if (t < 64) red[t] = fmaxf(red[t], red[t + 64]);
            __syncthreads();
            if (t < 32) red[t] = fmaxf(red[t], red[t + 32]);
            __syncthreads();
            if (t == 0) {
                float mx = red[0];
                for (int i = 1; i < 32; ++i) mx = fmaxf(mx, red[i]);
                KnSq[blockIdx.x] = mx;     // bx = g*16 + j
            }
        }
    } else {
        #pragma unroll
        for (int mc = 0; mc < 2; ++mc)
            #pragma unroll
            for (int nc = 0; nc < 4; ++nc)
                #pragma unroll
                for (int r = 0; r < 4; ++r)
                    Ash[(nc * 16 + r16) * 136 + w * 32 + mc * 16 + q4 * 4 + r] = f2bf(acc[mc][nc][r]);
        __syncthreads();
        const int g = m0 >> 11, s0 = m0 & 2047;
        int d = t >> 2, sb = (t & 3) * 32;
        u16* Out = Vt + ((size_t)(g * 64 + d)) * 2048 + s0;
        #pragma unroll
        for (int i = 0; i < 4; ++i)
            *(u32x4*)(Out + sb + i * 8) = *(const u32x4*)(Ash + d * 136 + sb + i * 8);
    }
}

// ---------------------------------------------------------------------------
// Kernel 2: flash attention, S^T orientation, fixed softmax bound, LDS
// double-buffered K/V tiles (64 keys/iter, 1 barrier/iter), XOR-swizzled
// LDS (chunk ck of row r stored at ck^(r&7); 16B chunks, no padding).
// ---------------------------------------------------------------------------
__global__ __launch_bounds__(256) void flash_kernel(
    const u16* __restrict__ Qb, const u16* __restrict__ Kb,
    const u16* __restrict__ Vt, const float* __restrict__ KnSq,
    u16* __restrict__ Att)
{
    const int g = blockIdx.y;    // 0..15
    const int qt = blockIdx.x;   // 0..31
    const int t = threadIdx.x, w = t >> 6, l = t & 63;
    const int r16 = l & 15, q4 = l >> 4;
    const int r7 = r16 & 7;

    __shared__ alignas(16) u16 Kt[2][64 * 64];   // [buf][row][swizzled chunks]
    __shared__ alignas(16) u16 Vs[2][64 * 64];
    __shared__ alignas(16) u16 Psh[4][16 * 64];  // per-wave P^T, swizzled

    const u16* Kg = Kb + ((size_t)g) * 2048 * 64;
    const u16* Vg = Vt + ((size_t)g) * 64 * 2048;

    // Q B-frag: B[n=q][k=d], lane n=r16, k=q4*8+j (+32)
    bf16x8 qb[2];
    {
        const u16* qp = Qb + ((size_t)(g * 2048 + qt * 64 + w * 16 + r16)) * 64 + q4 * 8;
        qb[0] = *(const bf16x8*)qp;
        qb[1] = *(const bf16x8*)(qp + 32);
    }

    // fixed bound m = ||Qrow_scaled|| * max_k||K_k|| * margin
    float m;
    {
        float kss = KnSq[g * 16 + r16];
        kss = fmaxf(kss, __shfl_xor(kss, 1));
        kss = fmaxf(kss, __shfl_xor(kss, 2));
        kss = fmaxf(kss, __shfl_xor(kss, 4));
        kss = fmaxf(kss, __shfl_xor(kss, 8));
        float ss = 0.f;
        #pragma unroll
        for (int kk = 0; kk < 2; ++kk)
            #pragma unroll
            for (int j = 0; j < 8; ++j) {
                float x = (float)qb[kk][j];
                ss += x * x;
            }
        ss += __shfl_xor(ss, 16);
        ss += __shfl_xor(ss, 32);
        m = sqrtf(ss) * sqrtf(kss) * 1.0002f;
    }

    // staging map: thread t -> rows rr, rr+32; chunk ck (global), ck^(row&7) (LDS)
    const int rr = t >> 3, ck = t & 7;
    const int sw0 = (ck ^ (rr & 7)) * 8;          // same for rr and rr+32

    {   // stage tile 0 into buf 0
        #pragma unroll
        for (int h = 0; h < 2; ++h) {
            int row = h * 32 + rr;
            *(u32x4*)(&Kt[0][row * 64 + sw0]) = *(const u32x4*)(Kg + (size_t)row * 64 + ck * 8);
            *(u32x4*)(&Vs[0][row * 64 + sw0]) = *(const u32x4*)(Vg + (size_t)row * 2048 + ck * 8);
        }
    }
    __syncthreads();

    f32x4 o[4];
    const f32x4 zero = {0.f, 0.f, 0.f, 0.f};
    #pragma unroll
    for (int dc = 0; dc < 4; ++dc) o[dc] = zero;
    float lsum = 0.f;

    u16* pw = &Psh[w][r16 * 64];
    // P write chunks: keys kc*16+q4*4 -> chunk 2kc + (q4>>1), swizzled, +4 u16 if q4 odd
    const int pq_off = (q4 & 1) * 4;
    // fragment read offsets (swizzled chunk for k-chunk q4+4kk of row r16-based)
    const int fr0 = ((q4 ^ r7)) * 8;
    const int fr1 = (((q4 + 4) & 7) ^ r7) * 8;   // q4+4 < 8 always

    for (int it = 0; it < 32; ++it) {
        const int cur = it & 1;
        const bool hasn = (it < 31);

        // register prefetch of next tile (coalesced)
        u32x4 knx[2], vnx[2];
        if (hasn) {
            #pragma unroll
            for (int h = 0; h < 2; ++h) {
                int row = h * 32 + rr;
                knx[h] = *(const u32x4*)(Kg + (size_t)((it + 1) * 64 + row) * 64 + ck * 8);
                vnx[h] = *(const u32x4*)(Vg + (size_t)row * 2048 + (it + 1) * 64 + ck * 8);
            }
        }

        // fragments from LDS (swizzled, conflict-free)
        const u16* Kc = Kt[cur];
        const u16* Vc = Vs[cur];
        bf16x8 ka[4][2], va[4][2];
        #pragma unroll
        for (int kc = 0; kc < 4; ++kc) {
            ka[kc][0] = *(const bf16x8*)(Kc + (kc * 16 + r16) * 64 + fr0);
            ka[kc][1] = *(const bf16x8*)(Kc + (kc * 16 + r16) * 64 + fr1);
        }
        #pragma unroll
        for (int dc = 0; dc < 4; ++dc) {
            va[dc][0] = *(const bf16x8*)(Vc + (dc * 16 + r16) * 64 + fr0);
            va[dc][1] = *(const bf16x8*)(Vc + (dc * 16 + r16) * 64 + fr1);
        }

        // S^T = K.Q^T : lane holds q-col r16, keys kc*16 + q4*4 + r
        f32x4 s[4];
        #pragma unroll
        for (int kc = 0; kc < 4; ++kc) {
            s[kc] = zero;
            s[kc] = __builtin_amdgcn_mfma_f32_16x16x32_bf16(ka[kc][0], qb[0], s[kc], 0, 0, 0);
            s[kc] = __builtin_amdgcn_mfma_f32_16x16x32_bf16(ka[kc][1], qb[1], s[kc], 0, 0, 0);
        }

        // p = exp2(s - m); per-lane lsum (no reductions, no rescale)
        float p[4][4];
        float psum = 0.f;
        #pragma unroll
        for (int kc = 0; kc < 4; ++kc)
            #pragma unroll
            for (int r = 0; r < 4; ++r) {
                p[kc][r] = exp2f(s[kc][r] - m);
                psum += p[kc][r];
            }
        lsum += psum;

        // P^T (C-layout) -> per-wave swizzled LDS -> B-frag
        #pragma unroll
        for (int kc = 0; kc < 4; ++kc) {
            uint2 dd = { pack2bf(p[kc][0], p[kc][1]), pack2bf(p[kc][2], p[kc][3]) };
            int sc = ((2 * kc + (q4 >> 1)) ^ r7) * 8 + pq_off;
            *(uint2*)(pw + sc) = dd;
        }
        bf16x8 pb0 = *(const bf16x8*)(pw + fr0);
        bf16x8 pb1 = *(const bf16x8*)(pw + fr1);

        // O^T += V^T . P^T
        #pragma unroll
        for (int dc = 0; dc < 4; ++dc) {
            o[dc] = __builtin_amdgcn_mfma_f32_16x16x32_bf16(va[dc][0], pb0, o[dc], 0, 0, 0);
            o[dc] = __builtin_amdgcn_mfma_f32_16x16x32_bf16(va[dc][1], pb1, o[dc], 0, 0, 0);
        }

        // stage next tile into buf^1
        if (hasn) {
            const int nxt = cur ^ 1;
            #pragma unroll
            for (int h = 0; h < 2; ++h) {
                int row = h * 32 + rr;
                *(u32x4*)(&Kt[nxt][row * 64 + sw0]) = knx[h];
                *(u32x4*)(&Vs[nxt][row * 64 + sw0]) = vnx[h];
            }
        }
        __syncthreads();
    }

    // epilogue: complete lsum across q4 groups, normalize, store
    float lt = lsum;
    lt += __shfl_xor(lt, 16);
    lt += __shfl_xor(lt, 32);
    float inv = 1.0f / lt;
    const int qq = qt * 64 + w * 16 + r16;
    u16* orow = Att + ((size_t)(g * 2048 + qq)) * 64;
    #pragma unroll
    for (int dc = 0; dc < 4; ++dc) {
        u16x4 bb = { f2bf(o[dc][0] * inv), f2bf(o[dc][1] * inv),
                     f2bf(o[dc][2] * inv), f2bf(o[dc][3] * inv) };
        *(u16x4*)(orow + dc * 16 + q4 * 4) = bb;
    }
}

// ---------------------------------------------------------------------------
// Kernel 3: out = Att @ Wb^T + bfc (Wb bf16).  Double-buffered coalesced LDS
// staging, XOR-swizzled fragment reads.  BM=64, BN=64, BK=64; grid (64,8).
// ---------------------------------------------------------------------------
__global__ __launch_bounds__(256) void fc_kernel(
    const u16* __restrict__ Att, const u16* __restrict__ Wb,
    const float* __restrict__ bfc, float* __restrict__ out)
{
    __shared__ alignas(16) u16 Ash[2][64 * 64];
    __shared__ alignas(16) u16 Wsh[2][64 * 64];

    const int t = threadIdx.x, w = t >> 6, l = t & 63;
    const int r16 = l & 15, q4 = l >> 4;
    const int r7 = r16 & 7;
    const int m0 = blockIdx.x * 64, n0 = blockIdx.y * 64;

    const int rr = t >> 3, ck = t & 7;
    const int sw0 = (ck ^ (rr & 7)) * 8;
    const int fr0 = (q4 ^ r7) * 8;
    const int fr1 = ((q4 + 4) ^ r7) * 8;

    {   // stage k0 = 0 into buf 0
        #pragma unroll
        for (int h = 0; h < 2; ++h) {
            int row = h * 32 + rr;
            *(u32x4*)(&Ash[0][row * 64 + sw0]) = *(const u32x4*)(Att + (size_t)(m0 + row) * 512 + ck * 8);
            *(u32x4*)(&Wsh[0][row * 64 + sw0]) = *(const u32x4*)(Wb + (size_t)(n0 + row) * 512 + ck * 8);
        }
    }
    __syncthreads();

    f32x4 acc[4];
    const f32x4 zero = {0.f, 0.f, 0.f, 0.f};
    #pragma unroll
    for (int nc = 0; nc < 4; ++nc) acc[nc] = zero;

    for (int it = 0; it < 8; ++it) {
        const int cur = it & 1;
        const bool hasn = (it < 7);

        u32x4 anx[2], wnx[2];
        if (hasn) {
            #pragma unroll
            for (int h = 0; h < 2; ++h) {
                int row = h * 32 + rr;
                anx[h] = *(const u32x4*)(Att + (size_t)(m0 + row) * 512 + (it + 1) * 64 + ck * 8);
                wnx[h] = *(const u32x4*)(Wb + (size_t)(n0 + row) * 512 + (it + 1) * 64 + ck * 8);
            }
        }

        bf16x8 af[2], wf[4][2];
        af[0] = *(const bf16x8*)(&Ash[cur][(w * 16 + r16) * 64 + fr0]);
        af[1] = *(const bf16x8*)(&Ash[cur][(w * 16 + r16) * 64 + fr1]);
        #pragma unroll
        for (int nc = 0; nc < 4; ++nc) {
            wf[nc][0] = *(const bf16x8*)(&Wsh[cur][(nc * 16 + r16) * 64 + fr0]);
            wf[nc][1] = *(const bf16x8*)(&Wsh[cur][(nc * 16 + r16) * 64 + fr1]);
        }

        #pragma unroll
        for (int nc = 0; nc < 4; ++nc) {
            acc[nc] = __builtin_amdgcn_mfma_f32_16x16x32_bf16(af[0], wf[nc][0], acc[nc], 0, 0, 0);
            acc[nc] = __builtin_amdgcn_mfma_f32_16x16x32_bf16(af[1], wf[nc][1], acc[nc], 0, 0, 0);
        }

        if (hasn) {
            const int nxt = cur ^ 1;
            #pragma unroll
            for (int h = 0; h < 2; ++h) {
                int row = h * 32 + rr;
                *(u32x4*)(&Ash[nxt][row * 64 + sw0]) = anx[h];
                *(u32x4*)(&Wsh[nxt][row * 64 + sw0]) = wnx[h];
            }
        }
        __syncthreads();
    }

    #pragma unroll
    for (int nc = 0; nc < 4; ++nc) {
        float bb = bfc[n0 + nc * 16 + r16];
        #pragma unroll
        for (int r = 0; r < 4; ++r) {
            int row = m0 + w * 16 + q4 * 4 + r;
            out[(size_t)row * 512 + n0 + nc * 16 + r16] = acc[nc][r] + bb;
        }
    }
}

extern "C" void kernel_launch(void* const* d_in, const int* in_sizes, int n_in,
                              void* d_out, int out_size, void* d_ws, size_t ws_size,
                              hipStream_t stream) {
    (void)in_sizes; (void)n_in; (void)out_size; (void)ws_size;
    const float* q   = (const float*)d_in[0];
    const float* k   = (const float*)d_in[1];
    const float* v   = (const float*)d_in[2];
    const float* Wq  = (const float*)d_in[3];
    const float* Wk  = (const float*)d_in[4];
    const float* Wv  = (const float*)d_in[5];
    const float* Wfc = (const float*)d_in[6];
    const float* bfc = (const float*)d_in[7];
    float* out = (float*)d_out;

    u16* Qb = (u16*)d_ws;
    u16* Kb = Qb + 2097152;
    u16* Vt = Kb + 2097152;
    u16* At = Vt + 2097152;
    u16* Wb = At + 2097152;                         // 512 KiB
    float* KnSq = (float*)((char*)d_ws + 17301504); // 256 floats

    proj_kernel<<<dim3(256, 1, 4), 256, 0, stream>>>(q, k, v, Wq, Wk, Wv, Wfc,
                                                     Qb, Kb, Vt, Wb, KnSq);
    flash_kernel<<<dim3(32, 16), 256, 0, stream>>>(Qb, Kb, Vt, KnSq, At);
    fc_kernel<<<dim3(64, 8), 256, 0, stream>>>(At, Wb, bfc, out);
}